// Round 3
// baseline (277.720 us; speedup 1.0000x reference)
//
#include <hip/hip_runtime.h>

// R11 = R10 with the indexing bug fixed: global float2 index of x[b][t][c2] is
// r_global*C2 + c2 (batch offset already inside r0) -- R10 double-added lo2.
// Theory under test (unchanged): output row r is the CONTIGUOUS input slice
// x[b, r-9 : r+10, :]; 19x input reuse is served by L1/L2, so the LDS
// round-trip bought nothing but a barrier. Pure streaming copy: per row one
// L1-hit global_load_dwordx2 + one ALLOCATING global_store_dwordx2, no sync.
// Keeps R8's reverse tile order (poison-drain cancellation) -- R9 proved nt
// stores forfeit it (273 us).
// Predict: dur_us 248 -> 238-242 if barrier/staging overhead was real;
// neutral +-3 if window is store-drain-bound (then roofline); >253 revert.

constexpr int N_CONTEXT = 9;
constexpr int C         = 26;                 // N_INPUT
constexpr int WINDOW    = 2 * N_CONTEXT + 1;  // 19
constexpr int BATCH     = 64;
constexpr int TIME      = 2000;
constexpr int ROW       = WINDOW * C;         // 494 floats per output row
constexpr int ROW2      = ROW / 2;            // 247 float2 columns per row
constexpr int C2        = C / 2;              // 13 float2 per time step

constexpr int T_TILE    = 40;                    // 40 | 2000 -> batch-uniform tiles
constexpr int BLOCK     = 256;
constexpr int NBLOCKS   = BATCH * TIME / T_TILE; // 3200
constexpr int BATCH_F2  = TIME * C2;             // 26000 float2 per batch

typedef float f32x2 __attribute__((ext_vector_type(2)));

__global__ __launch_bounds__(BLOCK)
void CreateOverlappingWindows_84963043050043_kernel(const float* __restrict__ x,
                                                    float* __restrict__ out) {
    const int tid  = threadIdx.x;
    if (tid >= ROW2) return;                       // no barrier -> early exit ok
    const int tile = (NBLOCKS - 1) - blockIdx.x;   // REVERSE dispatch order (R8)
    const int r0   = tile * T_TILE;          // first output row of tile (global)
    const int b    = r0 / TIME;              // batch (tile is batch-uniform)
    const int lo2  = b * BATCH_F2;           // valid float2 range for batch

    const f32x2* x2 = reinterpret_cast<const f32x2*>(x);
    // float2 index of (row r0, window col pair tid): batch offset is already
    // contained in r0 (x[b][t][c2] flat = (b*TIME+t)*C2 + c2 = r*C2 + c2).
    const int gbase = (r0 - N_CONTEXT) * C2 + tid;

    f32x2* o2 = reinterpret_cast<f32x2*>(out) + (size_t)r0 * ROW2 + tid;

    #pragma unroll
    for (int lt = 0; lt < T_TILE; ++lt) {
        int g = gbase + lt * C2;
        f32x2 v = {0.0f, 0.0f};
        if ((unsigned)(g - lo2) < (unsigned)BATCH_F2) v = x2[g];
        o2[(size_t)lt * ROW2] = v;
    }
}

extern "C" void kernel_launch(void* const* d_in, const int* in_sizes, int n_in,
                              void* d_out, int out_size, void* d_ws, size_t ws_size,
                              hipStream_t stream) {
    const float* x = (const float*)d_in[0];
    float* out = (float*)d_out;
    CreateOverlappingWindows_84963043050043_kernel<<<NBLOCKS, BLOCK, 0, stream>>>(x, out);
}

// Round 4
// 251.890 us; speedup vs baseline: 1.1025x; 1.1025x over previous
//
#include <hip/hip_runtime.h>

// R12: R8's exact structure (LDS staging + reverse tile order + allocating
// float2 stores -- R9 proved nt loses drain-cancellation, R11 proved no-LDS
// loses store-pipe decoupling), with T_TILE 40 -> 100.
// Rationale: remaining ~18 us over the 40 us floor is per-tile overhead
// frequency. T_TILE=100: blocks 3200 -> 1280 (exactly 5/CU, no tail),
// halo re-fetch 1.45x -> 1.18x, 100 uninterrupted store rounds per barrier.
// LDS 6 -> 12 KB; occupancy stays thread-limited at 8 blocks/CU (isolated
// variable = block count).
// Predict: 248 -> 240-245 if per-tile overhead real; 246-252 neutral ->
// store-drain contention is the HW state (roofline next); >255 -> R8 final.

constexpr int N_CONTEXT = 9;
constexpr int C         = 26;                 // N_INPUT
constexpr int WINDOW    = 2 * N_CONTEXT + 1;  // 19
constexpr int BATCH     = 64;
constexpr int TIME      = 2000;
constexpr int ROW       = WINDOW * C;         // 494 floats per output row
constexpr int ROW2      = ROW / 2;            // 247 float2 columns per row
constexpr int C2        = C / 2;              // 13 float2 per time step

constexpr int T_TILE    = 100;                   // 100 | 2000 -> batch-uniform
constexpr int LDS_ROWS  = T_TILE + WINDOW - 1;   // 118 time steps staged
constexpr int LDS_F2    = LDS_ROWS * C2;         // 1534 float2 (12.3 KB)
constexpr int BLOCK     = 256;
constexpr int NBLOCKS   = BATCH * TIME / T_TILE; // 1280 = 5 * 256
constexpr int BATCH_F2  = TIME * C2;             // 26000 float2 per batch

typedef float f32x2 __attribute__((ext_vector_type(2)));

__global__ __launch_bounds__(BLOCK)
void CreateOverlappingWindows_84963043050043_kernel(const float* __restrict__ x,
                                                    float* __restrict__ out) {
    __shared__ f32x2 lds2[LDS_F2];
    const int tid  = threadIdx.x;
    const int tile = (NBLOCKS - 1) - blockIdx.x;   // REVERSE dispatch order
    const int r0   = tile * T_TILE;          // first output row of tile
    const int b    = r0 / TIME;              // batch (tile is batch-uniform)
    const int lo2  = b * BATCH_F2;           // valid float2 range for batch
    const int base2 = (r0 - N_CONTEXT) * C2;
    const f32x2* x2 = reinterpret_cast<const f32x2*>(x);

    // Phase 1: stage x[b, r0-9 .. r0+T_TILE-1+9, :] as float2; zeros at batch
    // edges via one unsigned range check (boundaries are float2-aligned).
    #pragma unroll
    for (int it = 0; it < (LDS_F2 + BLOCK - 1) / BLOCK; ++it) {
        int idx = tid + it * BLOCK;
        if (idx < LDS_F2) {
            int g = base2 + idx;
            f32x2 v = {0.0f, 0.0f};
            if ((unsigned)(g - lo2) < (unsigned)BATCH_F2) v = x2[g];
            lds2[idx] = v;
        }
    }
    __syncthreads();

    // Phase 2: thread = column pair, loop = rows. One ds_read_b64 + one
    // independent allocating global_store_dwordx2 per row; no index math.
    // Proven 6.87 TB/s steady-state in the R7 multi-pass diagnostic.
    if (tid < ROW2) {
        f32x2* o2 = reinterpret_cast<f32x2*>(out) + (size_t)r0 * ROW2 + tid;
        #pragma unroll 20
        for (int lt = 0; lt < T_TILE; ++lt) {
            o2[(size_t)lt * ROW2] = lds2[lt * C2 + tid];
        }
    }
}

extern "C" void kernel_launch(void* const* d_in, const int* in_sizes, int n_in,
                              void* d_out, int out_size, void* d_ws, size_t ws_size,
                              hipStream_t stream) {
    const float* x = (const float*)d_in[0];
    float* out = (float*)d_out;
    CreateOverlappingWindows_84963043050043_kernel<<<NBLOCKS, BLOCK, 0, stream>>>(x, out);
}

// Round 5
// 248.460 us; speedup vs baseline: 1.1178x; 1.0138x over previous
//
#include <hip/hip_runtime.h>

// R13 = byte-identical revert to R8 (best measured: 247.9 us).
// Session evidence that this is the floor:
//   R9  (nt stores):        273 us -- non-temporal forfeits poison-drain
//                           cancellation; allocating stores overwrite dirty
//                           poison lines in cache.
//   R11 (no LDS):           278 us -- direct copy puts loads and stores on the
//                           same vector-mem pipe; LDS staging decouples them.
//   R12 (T_TILE 100):       252 us -- 2.5x fewer barriers/blocks, less halo
//                           re-fetch: neutral. Per-tile overhead is not the gap.
// Roofline: fill 988 MB (~152 us, harness) + restores/gaps (~38 us, harness)
// + kernel 266 MB (40 us floor, ~58 us in-situ under concurrent poison-drain
// arbitration) => ~241 us structural floor; R8 = 247.9 is within ~3%.

constexpr int N_CONTEXT = 9;
constexpr int C         = 26;                 // N_INPUT
constexpr int WINDOW    = 2 * N_CONTEXT + 1;  // 19
constexpr int BATCH     = 64;
constexpr int TIME      = 2000;
constexpr int ROW       = WINDOW * C;         // 494 floats per output row
constexpr int ROW2      = ROW / 2;            // 247 float2 columns per row
constexpr int C2        = C / 2;              // 13 float2 per time step

constexpr int T_TILE    = 40;                    // 40 | 2000 -> batch-uniform tiles
constexpr int LDS_ROWS  = T_TILE + WINDOW - 1;   // 58 time steps staged
constexpr int LDS_F2    = LDS_ROWS * C2;         // 754 float2 (6 KB)
constexpr int BLOCK     = 256;
constexpr int NBLOCKS   = BATCH * TIME / T_TILE; // 3200
constexpr int BATCH_F2  = TIME * C2;             // 26000 float2 per batch

__global__ __launch_bounds__(BLOCK)
void CreateOverlappingWindows_84963043050043_kernel(const float* __restrict__ x,
                                                    float* __restrict__ out) {
    __shared__ float2 lds2[LDS_F2];
    const int tid  = threadIdx.x;
    const int tile = (NBLOCKS - 1) - blockIdx.x;   // REVERSE dispatch order
    const int r0   = tile * T_TILE;          // first output row of tile
    const int b    = r0 / TIME;              // batch (tile is batch-uniform)
    const int lo2  = b * BATCH_F2;           // valid float2 range for batch
    const int base2 = ((r0 - N_CONTEXT) * C) >> 1;
    const float2* x2 = reinterpret_cast<const float2*>(x);

    // Phase 1: stage x[b, r0-9 .. r0+39+9, :] as float2; zeros materialized at
    // batch edges (single unsigned range check, boundaries float2-aligned).
    #pragma unroll
    for (int it = 0; it < (LDS_F2 + BLOCK - 1) / BLOCK; ++it) {
        int idx = tid + it * BLOCK;
        if (idx < LDS_F2) {
            int g = base2 + idx;
            float2 v = make_float2(0.0f, 0.0f);
            if ((unsigned)(g - lo2) < (unsigned)BATCH_F2) v = x2[g];
            lds2[idx] = v;
        }
    }
    __syncthreads();

    // Phase 2: thread = column pair, loop = rows. One ds_read_b64 (16-bit imm
    // offset) + one independent global_store_dwordx2 per row; no index math.
    // Proven at 6.87 TB/s steady-state in the R7 multi-pass diagnostic.
    if (tid < ROW2) {
        float2* o2 = reinterpret_cast<float2*>(out) + (size_t)r0 * ROW2 + tid;
        #pragma unroll
        for (int lt = 0; lt < T_TILE; ++lt) {
            o2[(size_t)lt * ROW2] = lds2[lt * C2 + tid];
        }
    }
}

extern "C" void kernel_launch(void* const* d_in, const int* in_sizes, int n_in,
                              void* d_out, int out_size, void* d_ws, size_t ws_size,
                              hipStream_t stream) {
    const float* x = (const float*)d_in[0];
    float* out = (float*)d_out;
    CreateOverlappingWindows_84963043050043_kernel<<<NBLOCKS, BLOCK, 0, stream>>>(x, out);
}